// Round 6
// baseline (180.742 us; speedup 1.0000x reference)
//
#include <hip/hip_runtime.h>
#include <hip/hip_cooperative_groups.h>
#include <stdint.h>

namespace cg = cooperative_groups;

// Problem constants (fixed by the reference).
#define BB 4
#define NN 4096
#define MM 4096
#define CC 16
#define KMAX 128

// Output layout (flat float32, reference return order).
static constexpr int LOCSR_OFF = 0;                        // B*N*3
static constexpr int DATAR_OFF = BB * NN * 3;              // 49152
static constexpr int IDXS_OFF  = DATAR_OFF + BB * NN * CC; // 311296
static constexpr int NB_OFF    = IDXS_OFF + BB * NN;       // 327680

// radius as f32 (jnp weak-scalar cast), R^2 as double product cast to f32
static constexpr float RAD_F = 0.14f;
static constexpr float R2F   = (float)(0.14 * 0.14);

// Hash-grid limits
static constexpr int MAXC    = 96 * 96 * 96;   // max cells per batch
static constexpr int CSTRIDE = MAXC + 8;       // cell_start stride per batch

__device__ inline void axis_range(float qd, float lo, int gd, int* c0, int* c1) {
    const float DL = RAD_F + 1e-4f; // conservative margin >> all fp rounding
    float vlo = (qd - DL - lo) / RAD_F;
    float vhi = (qd + DL - lo) / RAD_F;
    int a = (int)floorf(vlo), b = (int)floorf(vhi);
    *c0 = min(max(a, 0), gd - 1);
    *c1 = min(max(b, 0), gd - 1);
}

// ---------------- Single cooperative kernel: bbox -> params/keys/rank/scatter
// -> cell_start -> neighbors, with grid.sync() between phases. 256 blocks x
// 1024 threads = 1 block/CU (co-residency guaranteed by __launch_bounds__
// (1024,4) -> VGPR<=128). Block blk owns batch b=blk>>6 in every phase.
// All fp op sequences identical to the 4-kernel harness-verified version.
__global__ void __launch_bounds__(1024, 4)
k_mega(const float* __restrict__ locs,
       const float* __restrict__ data,
       const float* __restrict__ qlocs,
       float* __restrict__ out,
       float* __restrict__ pmm,
       unsigned* __restrict__ cs_sorted,
       float4* __restrict__ sp4,
       int* __restrict__ cell_start) {
    cg::grid_group grid = cg::this_grid();
    __shared__ uint4 keys4[NN / 4];  // 16 KB
    __shared__ int partial[16][64];  // 4 KB
    __shared__ int s_dst[64];
    __shared__ float sp_low[3], sp_gdf[3];
    __shared__ int sp_gdi[3], sp_s0, sp_s1, sp_nc;

    int blk = blockIdx.x;            // 256 blocks
    int b = blk >> 6;                // batch
    int t = threadIdx.x;
    int wave = t >> 6, lane = t & 63;

    // ---- Phase A: bbox partial over this block's 64-particle slice (wave 0) ----
    if (wave == 0) {
        int slice = blk & 63;
        const float* p = locs + (b * NN + slice * 64 + lane) * 3;
        float mn0 = p[0], mn1 = p[1], mn2 = p[2];
        float mx0 = mn0, mx1 = mn1, mx2 = mn2;
#pragma unroll
        for (int off = 32; off > 0; off >>= 1) {
            mn0 = fminf(mn0, __shfl_xor(mn0, off));
            mn1 = fminf(mn1, __shfl_xor(mn1, off));
            mn2 = fminf(mn2, __shfl_xor(mn2, off));
            mx0 = fmaxf(mx0, __shfl_xor(mx0, off));
            mx1 = fmaxf(mx1, __shfl_xor(mx1, off));
            mx2 = fmaxf(mx2, __shfl_xor(mx2, off));
        }
        if (lane == 0) {
            float* o = pmm + blk * 6;
            o[0] = mn0; o[1] = mn1; o[2] = mn2;
            o[3] = mx0; o[4] = mx1; o[5] = mx2;
        }
    }
    grid.sync();

    // ---- Phase B: params (t==0, deterministic & identical across the batch's
    // blocks), keys, stable rank sort, scatter ----
    if (t == 0) {
        const float* pm = pmm + b * 64 * 6;
        float mn0 = 1e30f, mn1 = 1e30f, mn2 = 1e30f;
        float mx0 = -1e30f, mx1 = -1e30f, mx2 = -1e30f;
#pragma unroll
        for (int k = 0; k < 64; ++k) {
            mn0 = fminf(mn0, pm[k * 6 + 0]);
            mn1 = fminf(mn1, pm[k * 6 + 1]);
            mn2 = fminf(mn2, pm[k * 6 + 2]);
            mx0 = fmaxf(mx0, pm[k * 6 + 3]);
            mx1 = fmaxf(mx1, pm[k * 6 + 4]);
            mx2 = fmaxf(mx2, pm[k * 6 + 5]);
        }
        float lo[3] = {mn0, mn1, mn2}, up[3] = {mx0, mx1, mx2};
#pragma unroll
        for (int d = 0; d < 3; ++d) {
            // EXACT op sequence from the verified kernel
            float u = __fdiv_rn(__fsub_rn(up[d], lo[d]), RAD_F);
            u = fminf(fmaxf(u, 0.0f), 96.0f);
            float g = ceilf(u);
            float center = __fmul_rn(__fadd_rn(lo[d], up[d]), 0.5f);
            sp_low[d] = __fsub_rn(center, __fmul_rn(__fmul_rn(g, RAD_F), 0.5f));
            sp_gdf[d] = g;
            sp_gdi[d] = max((int)g, 1);
        }
        sp_s0 = sp_gdi[1] * sp_gdi[2];
        sp_s1 = sp_gdi[2];
        sp_nc = sp_gdi[0] * sp_gdi[1] * sp_gdi[2];
    }
    __syncthreads();

    // Keys for elements 4t..4t+3 via three coalesced float4 loads.
    {
        float l0 = sp_low[0], l1 = sp_low[1], l2 = sp_low[2];
        float g0 = sp_gdf[0], g1 = sp_gdf[1], g2 = sp_gdf[2];
        int s0 = sp_s0, s1 = sp_s1;
        const float4* lp = (const float4*)(locs + b * NN * 3) + t * 3;
        float4 A = lp[0], Bv = lp[1], Cv = lp[2];
        float ex[4] = {A.x, A.w, Bv.z, Cv.y};
        float ey[4] = {A.y, Bv.x, Bv.w, Cv.z};
        float ez[4] = {A.z, Bv.y, Cv.x, Cv.w};
        unsigned kk[4];
#pragma unroll
        for (int j = 0; j < 4; ++j) {
            float c0 = fminf(fmaxf(floorf(__fdiv_rn(__fsub_rn(ex[j], l0), RAD_F)), 0.0f), __fsub_rn(g0, 1.0f));
            float c1 = fminf(fmaxf(floorf(__fdiv_rn(__fsub_rn(ey[j], l1), RAD_F)), 0.0f), __fsub_rn(g1, 1.0f));
            float c2 = fminf(fmaxf(floorf(__fdiv_rn(__fsub_rn(ez[j], l2), RAD_F)), 0.0f), __fsub_rn(g2, 1.0f));
            unsigned cell = (unsigned)((int)c0 * s0 + (int)c1 * s1 + (int)c2);
            kk[j] = cell * 4096u + (unsigned)(4 * t + j);
        }
        keys4[t] = make_uint4(kk[0], kk[1], kk[2], kk[3]);
    }
    __syncthreads();

    int i = (blk & 63) * 64 + lane;
    unsigned key = ((const unsigned*)keys4)[i];
    // Wave's 256-key chunk held in registers: one b128 per lane.
    uint4 mv = keys4[wave * 64 + lane];
    int rank = 0;
#pragma unroll
    for (int s = 0; s < 64; ++s) {
        unsigned a  = (unsigned)__builtin_amdgcn_readlane((int)mv.x, s);
        unsigned b2 = (unsigned)__builtin_amdgcn_readlane((int)mv.y, s);
        unsigned c2 = (unsigned)__builtin_amdgcn_readlane((int)mv.z, s);
        unsigned d2 = (unsigned)__builtin_amdgcn_readlane((int)mv.w, s);
        rank += (int)(a < key) + (int)(b2 < key) + (int)(c2 < key) + (int)(d2 < key);
    }
    partial[wave][lane] = rank;
    __syncthreads();
    if (wave == 0) {
        int r = 0;
#pragma unroll
        for (int w = 0; w < 16; ++w) r += partial[w][lane];
        s_dst[lane] = r;
    }
    __syncthreads();
    if (wave == 0) {
        int src = b * NN + i;
        int dst = b * NN + s_dst[lane];
        float x = locs[src * 3 + 0], y = locs[src * 3 + 1], z = locs[src * 3 + 2];
        out[IDXS_OFF + dst] = (float)i;        // idxs[new] = old (as f32)
        out[LOCSR_OFF + dst * 3 + 0] = x;
        out[LOCSR_OFF + dst * 3 + 1] = y;
        out[LOCSR_OFF + dst * 3 + 2] = z;
        cs_sorted[dst] = key;                  // combined key; cell = key>>12
        // pn = (x*x + y*y) + z*z, numpy pairwise-sum (forward) order
        float pn = __fadd_rn(__fadd_rn(__fmul_rn(x, x), __fmul_rn(y, y)), __fmul_rn(z, z));
        sp4[dst] = make_float4(x, y, z, pn);
    } else if (wave <= 4) {
        int p = lane;
        int ii = (blk & 63) * 64 + p;
        int dst = b * NN + s_dst[p];
        int c = wave - 1;
        const float4* dsrc = (const float4*)(data + (b * NN + ii) * 16);
        float4* ddst = (float4*)(out + DATAR_OFF + dst * 16);
        ddst[c] = dsrc[c];
    }
    grid.sync();

    // ---- Phase C: cell_start via binary search (64 blocks x 1024 thr / batch) ----
    {
        int nc = sp_nc;
        const unsigned* cs = cs_sorted + b * NN;
        int* cst = cell_start + b * CSTRIDE;
        for (int c = (blk & 63) * 1024 + t; c <= nc; c += 64 * 1024) {
            int lo = 0, hi = NN; // first index with cell(cs[idx]) >= c
            while (lo < hi) {
                int mid = (lo + hi) >> 1;
                if ((int)(cs[mid] >> 12) < c) lo = mid + 1; else hi = mid;
            }
            cst[c] = lo;
        }
    }
    grid.sync();

    // ---- Phase D: neighbors, 4 queries per wave (64 queries per block) ----
    {
        int s0 = sp_s0, s1 = sp_s1;
        int gd0 = sp_gdi[0], gd1 = sp_gdi[1], gd2 = sp_gdi[2];
        float lo0 = sp_low[0], lo1 = sp_low[1], lo2 = sp_low[2];
        const float4* sp = sp4 + b * NN;
        const int* cst = cell_start + b * CSTRIDE;
#pragma unroll 1
        for (int j = 0; j < 4; ++j) {
            int m = (blk & 63) * 64 + wave * 4 + j;
            const float* q = qlocs + (b * MM + m) * 3;
            float q0 = q[0], q1 = q[1], q2 = q[2];
            float qn = __fadd_rn(__fadd_rn(__fmul_rn(q0, q0), __fmul_rn(q1, q1)), __fmul_rn(q2, q2));
            int cx0, cx1, cy0, cy1, cz0, cz1;
            axis_range(q0, lo0, gd0, &cx0, &cx1);
            axis_range(q1, lo1, gd1, &cy0, &cy1);
            axis_range(q2, lo2, gd2, &cz0, &cz1);
            float* nb = out + NB_OFF + (b * MM + m) * KMAX;

            // 9 column ranges (fixed 3x3, invalid -> empty) + exclusive prefix.
            int ps_[9], pe_[9];
#pragma unroll
            for (int dx = 0; dx < 3; ++dx) {
#pragma unroll
                for (int dy = 0; dy < 3; ++dy) {
                    int k = dx * 3 + dy;
                    int cx = cx0 + dx, cy = cy0 + dy;
                    bool v = (cx <= cx1) && (cy <= cy1);
                    int base = cx * s0 + cy * s1;
                    int i0 = v ? base + cz0 : 0;
                    int i1 = v ? base + cz1 + 1 : 0;
                    int a = cst[i0];
                    int e = cst[i1];
                    ps_[k] = v ? a : 0;
                    pe_[k] = v ? e : 0;
                }
            }
            int pre_[10];
            pre_[0] = 0;
#pragma unroll
            for (int k = 0; k < 9; ++k) pre_[k + 1] = pre_[k] + max(pe_[k] - ps_[k], 0);
            int T = pre_[9];

            int count = 0;
            for (int l0i = 0; l0i < T; l0i += 64) {
                int l = l0i + lane;
                int p = 0;
#pragma unroll
                for (int k = 0; k < 9; ++k) {
                    bool in = (l >= pre_[k]) && (l < pre_[k + 1]);
                    p = in ? (ps_[k] + (l - pre_[k])) : p;
                }
                float4 P = sp[p];
                float cross = fmaf(q2, P.z, fmaf(q1, P.y, __fmul_rn(q0, P.x)));
                float dist2 = __fsub_rn(__fadd_rn(qn, P.w), __fmul_rn(2.0f, cross));
                bool hit = (l < T) && (dist2 <= R2F);
                unsigned long long bal = __ballot(hit);
                if (hit) {
                    int pos = count + __popcll(bal & ((1ull << lane) - 1ull));
                    if (pos < KMAX) nb[pos] = (float)p;
                }
                count += __popcll(bal);
                if (count >= KMAX) break; // wave-uniform
            }
            for (int jj = count + lane; jj < KMAX; jj += 64) nb[jj] = -1.0f;
        }
    }
}

extern "C" void kernel_launch(void* const* d_in, const int* in_sizes, int n_in,
                              void* d_out, int out_size, void* d_ws, size_t ws_size,
                              hipStream_t stream) {
    const float* locs  = (const float*)d_in[0];
    const float* data  = (const float*)d_in[1];
    const float* qlocs = (const float*)d_in[2];
    float* out = (float*)d_out;
    char* ws = (char*)d_ws;
    // ws layout
    float*    pmm       = (float*)ws;                          // 256*6 floats (8 KB reserved)
    unsigned* cs_sorted = (unsigned*)(ws + 8192);              // 64 KB
    float4*   sp4       = (float4*)(ws + 8192 + 65536);        // 256 KB (16B aligned)
    int* cell_start = (int*)(ws + 8192 + 65536 + BB * NN * sizeof(float4)); // ~14 MB

    void* args[] = {(void*)&locs, (void*)&data, (void*)&qlocs, (void*)&out,
                    (void*)&pmm, (void*)&cs_sorted, (void*)&sp4, (void*)&cell_start};
    hipLaunchCooperativeKernel(reinterpret_cast<void*>(k_mega),
                               dim3(256), dim3(1024), args, 0, stream);
}

// Round 7
// 91.481 us; speedup vs baseline: 1.9757x; 1.9757x over previous
//
#include <hip/hip_runtime.h>
#include <stdint.h>

// Problem constants (fixed by the reference).
#define BB 4
#define NN 4096
#define MM 4096
#define CC 16
#define KMAX 128

// Output layout (flat float32, reference return order).
static constexpr int LOCSR_OFF = 0;                        // B*N*3
static constexpr int DATAR_OFF = BB * NN * 3;              // 49152
static constexpr int IDXS_OFF  = DATAR_OFF + BB * NN * CC; // 311296
static constexpr int NB_OFF    = IDXS_OFF + BB * NN;       // 327680

// radius as f32 (jnp weak-scalar cast), R^2 as double product cast to f32
static constexpr float RAD_F = 0.14f;
static constexpr float R2F   = (float)(0.14 * 0.14);

// ---------------- K0: per-batch partial bbox (16 blocks/batch) ----------------
__global__ void __launch_bounds__(256) k_bbox(const float* __restrict__ locs,
                                              float* __restrict__ pmm) {
    int blk = blockIdx.x;
    int b = blk >> 4, s = blk & 15, t = threadIdx.x;
    int i = s * 256 + t;
    const float* p = locs + (b * NN + i) * 3;
    float x0 = p[0], x1 = p[1], x2 = p[2];
    __shared__ float sm[6][256];
    sm[0][t] = x0; sm[1][t] = x1; sm[2][t] = x2;
    sm[3][t] = x0; sm[4][t] = x1; sm[5][t] = x2;
    __syncthreads();
    for (int st = 128; st > 0; st >>= 1) {
        if (t < st) {
            sm[0][t] = fminf(sm[0][t], sm[0][t + st]);
            sm[1][t] = fminf(sm[1][t], sm[1][t + st]);
            sm[2][t] = fminf(sm[2][t], sm[2][t + st]);
            sm[3][t] = fmaxf(sm[3][t], sm[3][t + st]);
            sm[4][t] = fmaxf(sm[4][t], sm[4][t + st]);
            sm[5][t] = fmaxf(sm[5][t], sm[5][t + st]);
        }
        __syncthreads();
    }
    if (t == 0) {
        float* o = pmm + blk * 6;
        o[0] = sm[0][0]; o[1] = sm[1][0]; o[2] = sm[2][0];
        o[3] = sm[3][0]; o[4] = sm[4][0]; o[5] = sm[5][0];
    }
}

// ---------------- K1: params + keys + stable rank sort + scatter ----------------
__global__ void __launch_bounds__(1024) k_rank(const float* __restrict__ locs,
                                               const float* __restrict__ data,
                                               const float* __restrict__ pmm,
                                               float* __restrict__ out,
                                               float4* __restrict__ sp4,
                                               unsigned* __restrict__ cs_sorted,
                                               float* __restrict__ gp) {
    __shared__ uint4 keys4[NN / 4];  // 16 KB
    __shared__ int partial[16][64];  // 4 KB
    __shared__ int s_dst[64];
    __shared__ float sp_low[3], sp_gdf[3];
    __shared__ int sp_s0, sp_s1;
    int blk = blockIdx.x;
    int b = blk >> 6;
    int t = threadIdx.x;
    int wave = t >> 6, lane = t & 63;

    if (t == 0) {
        const float* pm = pmm + b * 96;
        float mn0 = 1e30f, mn1 = 1e30f, mn2 = 1e30f;
        float mx0 = -1e30f, mx1 = -1e30f, mx2 = -1e30f;
#pragma unroll
        for (int k = 0; k < 16; ++k) {
            mn0 = fminf(mn0, pm[k * 6 + 0]);
            mn1 = fminf(mn1, pm[k * 6 + 1]);
            mn2 = fminf(mn2, pm[k * 6 + 2]);
            mx0 = fmaxf(mx0, pm[k * 6 + 3]);
            mx1 = fmaxf(mx1, pm[k * 6 + 4]);
            mx2 = fmaxf(mx2, pm[k * 6 + 5]);
        }
        float lo[3] = {mn0, mn1, mn2}, up[3] = {mx0, mx1, mx2};
        float low2[3], gdf[3];
        int gdi[3];
#pragma unroll
        for (int d = 0; d < 3; ++d) {
            // EXACT op sequence from the verified kernel
            float u = __fdiv_rn(__fsub_rn(up[d], lo[d]), RAD_F);
            u = fminf(fmaxf(u, 0.0f), 96.0f);
            float g = ceilf(u);
            float center = __fmul_rn(__fadd_rn(lo[d], up[d]), 0.5f);
            low2[d] = __fsub_rn(center, __fmul_rn(__fmul_rn(g, RAD_F), 0.5f));
            gdf[d] = g;
            gdi[d] = max((int)g, 1);
        }
        sp_low[0] = low2[0]; sp_low[1] = low2[1]; sp_low[2] = low2[2];
        sp_gdf[0] = gdf[0];  sp_gdf[1] = gdf[1];  sp_gdf[2] = gdf[2];
        sp_s0 = gdi[1] * gdi[2];
        sp_s1 = gdi[2];
        if ((blk & 63) == 0) {
            float* o = gp + b * 12;
            o[0] = low2[0]; o[1] = low2[1]; o[2] = low2[2];
            o[3] = gdf[0];  o[4] = gdf[1];  o[5] = gdf[2];
            ((int*)o)[6]  = gdi[1] * gdi[2];
            ((int*)o)[7]  = gdi[2];
            ((int*)o)[8]  = gdi[0] * gdi[1] * gdi[2];
            ((int*)o)[9]  = gdi[0];
            ((int*)o)[10] = gdi[1];
            ((int*)o)[11] = gdi[2];
        }
    }
    __syncthreads();

    // Keys for elements 4t..4t+3 via three coalesced float4 loads.
    {
        float l0 = sp_low[0], l1 = sp_low[1], l2 = sp_low[2];
        float g0 = sp_gdf[0], g1 = sp_gdf[1], g2 = sp_gdf[2];
        int s0 = sp_s0, s1 = sp_s1;
        const float4* lp = (const float4*)(locs + b * NN * 3) + t * 3;
        float4 A = lp[0], Bv = lp[1], Cv = lp[2];
        float ex[4] = {A.x, A.w, Bv.z, Cv.y};
        float ey[4] = {A.y, Bv.x, Bv.w, Cv.z};
        float ez[4] = {A.z, Bv.y, Cv.x, Cv.w};
        unsigned kk[4];
#pragma unroll
        for (int j = 0; j < 4; ++j) {
            float c0 = fminf(fmaxf(floorf(__fdiv_rn(__fsub_rn(ex[j], l0), RAD_F)), 0.0f), __fsub_rn(g0, 1.0f));
            float c1 = fminf(fmaxf(floorf(__fdiv_rn(__fsub_rn(ey[j], l1), RAD_F)), 0.0f), __fsub_rn(g1, 1.0f));
            float c2 = fminf(fmaxf(floorf(__fdiv_rn(__fsub_rn(ez[j], l2), RAD_F)), 0.0f), __fsub_rn(g2, 1.0f));
            unsigned cell = (unsigned)((int)c0 * s0 + (int)c1 * s1 + (int)c2);
            kk[j] = cell * 4096u + (unsigned)(4 * t + j);
        }
        keys4[t] = make_uint4(kk[0], kk[1], kk[2], kk[3]);
    }
    __syncthreads();

    int i = (blk & 63) * 64 + lane;
    unsigned key = ((const unsigned*)keys4)[i];
    // Wave's 256-key chunk held in registers: one b128 per lane.
    uint4 mv = keys4[wave * 64 + lane];
    int rank = 0;
#pragma unroll
    for (int s = 0; s < 64; ++s) {
        unsigned a  = (unsigned)__builtin_amdgcn_readlane((int)mv.x, s);
        unsigned b2 = (unsigned)__builtin_amdgcn_readlane((int)mv.y, s);
        unsigned c2 = (unsigned)__builtin_amdgcn_readlane((int)mv.z, s);
        unsigned d2 = (unsigned)__builtin_amdgcn_readlane((int)mv.w, s);
        rank += (int)(a < key) + (int)(b2 < key) + (int)(c2 < key) + (int)(d2 < key);
    }
    partial[wave][lane] = rank;
    __syncthreads();
    if (wave == 0) {
        int r = 0;
#pragma unroll
        for (int w = 0; w < 16; ++w) r += partial[w][lane];
        s_dst[lane] = r;
    }
    __syncthreads();
    if (wave == 0) {
        int src = b * NN + i;
        int dst = b * NN + s_dst[lane];
        float x = locs[src * 3 + 0], y = locs[src * 3 + 1], z = locs[src * 3 + 2];
        out[IDXS_OFF + dst] = (float)i;        // idxs[new] = old (as f32)
        out[LOCSR_OFF + dst * 3 + 0] = x;
        out[LOCSR_OFF + dst * 3 + 1] = y;
        out[LOCSR_OFF + dst * 3 + 2] = z;
        cs_sorted[dst] = key;                  // combined key; cell = key>>12
        // pn = (x*x + y*y) + z*z, numpy pairwise-sum (forward) order
        float pn = __fadd_rn(__fadd_rn(__fmul_rn(x, x), __fmul_rn(y, y)), __fmul_rn(z, z));
        sp4[dst] = make_float4(x, y, z, pn);
    } else if (wave <= 4) {
        int p = lane;
        int ii = (blk & 63) * 64 + p;
        int dst = b * NN + s_dst[p];
        int c = wave - 1;
        const float4* dsrc = (const float4*)(data + (b * NN + ii) * 16);
        float4* ddst = (float4*)(out + DATAR_OFF + dst * 16);
        ddst[c] = dsrc[c];
    }
}

// ---------------- K2: grid-pruned radius search, wave per query ----------------
// cell_start dispatch eliminated: each block stages the batch's 16 KB sorted
// combined keys into LDS once; each query's 18 column bounds come from 12-step
// in-LDS binary searches (lanes 0-8 = starts, lanes 16-24 = ends; results
// broadcast via __shfl with compile-time lane ids). Search math identical to
// the old k_cellstart (lower_bound over keys >= c*4096) -> bit-exact outputs.
// Packed candidate list and dist2 math unchanged from the verified version.
__device__ inline void axis_range(float qd, float lo, int gd, int* c0, int* c1) {
    const float DL = RAD_F + 1e-4f; // conservative margin >> all fp rounding
    float vlo = (qd - DL - lo) / RAD_F;
    float vhi = (qd + DL - lo) / RAD_F;
    int a = (int)floorf(vlo), b = (int)floorf(vhi);
    *c0 = min(max(a, 0), gd - 1);
    *c1 = min(max(b, 0), gd - 1);
}

__global__ void __launch_bounds__(256, 6) k_neighbors(const float* __restrict__ qlocs,
                                                      const float4* __restrict__ sp4,
                                                      const unsigned* __restrict__ cs_sorted,
                                                      const float* __restrict__ gp,
                                                      float* __restrict__ out) {
    __shared__ uint4 skeys4[NN / 4];  // 16 KB: batch's sorted combined keys
    const unsigned* skeys = (const unsigned*)skeys4;

    int blk = blockIdx.x;        // 4096 total: b = blk>>10, 4 queries/block
    int b = blk >> 10;
    int t = threadIdx.x;
    int wave = t >> 6, lane = t & 63;

    // Stage cs_sorted[b] into LDS (coalesced uint4).
    {
        const uint4* g = (const uint4*)(cs_sorted + b * NN);
#pragma unroll
        for (int j = 0; j < 4; ++j) skeys4[t + 256 * j] = g[t + 256 * j];
    }

    int m = (blk & 1023) * 4 + wave;
    const float* o = gp + b * 12;
    const int* oi = (const int*)o;
    int s0 = oi[6], s1 = oi[7];
    int gd0 = oi[9], gd1 = oi[10], gd2 = oi[11];
    const float* q = qlocs + (b * MM + m) * 3;
    float q0 = q[0], q1 = q[1], q2 = q[2];
    float qn = __fadd_rn(__fadd_rn(__fmul_rn(q0, q0), __fmul_rn(q1, q1)), __fmul_rn(q2, q2));
    int cx0, cx1, cy0, cy1, cz0, cz1;
    axis_range(q0, o[0], gd0, &cx0, &cx1);
    axis_range(q1, o[1], gd1, &cy0, &cy1);
    axis_range(q2, o[2], gd2, &cz0, &cz1);
    const float4* sp = sp4 + b * NN;
    float* nb = out + NB_OFF + (b * MM + m) * KMAX;

    // Per-column cell-index bounds (all lanes compute all 9, const-indexed).
    unsigned t0_[9], t1_[9];
    bool va_[9];
#pragma unroll
    for (int dx = 0; dx < 3; ++dx) {
#pragma unroll
        for (int dy = 0; dy < 3; ++dy) {
            int k = dx * 3 + dy;
            int cx = cx0 + dx, cy = cy0 + dy;
            bool v = (cx <= cx1) && (cy <= cy1);
            int base = cx * s0 + cy * s1;
            va_[k] = v;
            t0_[k] = v ? (unsigned)(base + cz0) * 4096u : 0u;       // lower_bound target
            t1_[k] = v ? (unsigned)(base + cz1 + 1) * 4096u : 0u;
        }
    }
    __syncthreads();   // LDS staging complete

    // Lane k (k<9) searches start bound of column k; lane 16+k its end bound.
    unsigned tgt = 0u;
#pragma unroll
    for (int k = 0; k < 9; ++k) {
        tgt = (lane == k)      ? t0_[k] : tgt;
        tgt = (lane == 16 + k) ? t1_[k] : tgt;
    }
    int lo = 0, hi = NN;      // lower_bound: first idx with skeys[idx] >= tgt
#pragma unroll
    for (int it = 0; it < 12; ++it) {  // 4096 -> exactly 12 halvings
        int mid = (lo + hi) >> 1;
        unsigned v = skeys[mid];
        bool c = v < tgt;
        lo = c ? mid + 1 : lo;
        hi = c ? hi : mid;
    }
    int res = lo;

    // Broadcast bounds to all lanes; invalid columns -> empty.
    int ps_[9], pe_[9];
#pragma unroll
    for (int k = 0; k < 9; ++k) {
        int a = __shfl(res, k);
        int e = __shfl(res, 16 + k);
        ps_[k] = va_[k] ? a : 0;
        pe_[k] = va_[k] ? e : 0;
    }
    int pre_[10];
    pre_[0] = 0;
#pragma unroll
    for (int k = 0; k < 9; ++k) pre_[k + 1] = pre_[k] + max(pe_[k] - ps_[k], 0);
    int T = pre_[9];

    int count = 0;
    for (int l0i = 0; l0i < T; l0i += 64) {
        int l = l0i + lane;
        // Map packed index l -> sorted particle index p (unrolled select chain).
        int p = 0;
#pragma unroll
        for (int k = 0; k < 9; ++k) {
            bool in = (l >= pre_[k]) && (l < pre_[k + 1]);
            p = in ? (ps_[k] + (l - pre_[k])) : p;
        }
        float4 P = sp[p];
        float cross = fmaf(q2, P.z, fmaf(q1, P.y, __fmul_rn(q0, P.x)));
        float dist2 = __fsub_rn(__fadd_rn(qn, P.w), __fmul_rn(2.0f, cross));
        bool hit = (l < T) && (dist2 <= R2F);
        unsigned long long bal = __ballot(hit);
        if (hit) {
            int pos = count + __popcll(bal & ((1ull << lane) - 1ull));
            if (pos < KMAX) nb[pos] = (float)p;
        }
        count += __popcll(bal);
        if (count >= KMAX) break; // wave-uniform; remaining hits can't land
    }
    for (int j = count + lane; j < KMAX; j += 64) nb[j] = -1.0f;
}

extern "C" void kernel_launch(void* const* d_in, const int* in_sizes, int n_in,
                              void* d_out, int out_size, void* d_ws, size_t ws_size,
                              hipStream_t stream) {
    const float* locs  = (const float*)d_in[0];
    const float* data  = (const float*)d_in[1];
    const float* qlocs = (const float*)d_in[2];
    float* out = (float*)d_out;
    char* ws = (char*)d_ws;
    // ws layout
    float*    gp        = (float*)ws;                          // 4*12 floats (512 B reserved)
    float*    pmm       = (float*)(ws + 512);                  // 64*6 floats (4 KB reserved)
    unsigned* cs_sorted = (unsigned*)(ws + 4608);              // 64 KB
    float4*   sp4       = (float4*)(ws + 4608 + 65536);        // 256 KB (16B aligned)

    k_bbox<<<BB * 16, 256, 0, stream>>>(locs, pmm);
    k_rank<<<BB * 64, 1024, 0, stream>>>(locs, data, pmm, out, sp4, cs_sorted, gp);
    k_neighbors<<<BB * 1024, 256, 0, stream>>>(qlocs, sp4, cs_sorted, gp, out);
}

// Round 8
// 89.964 us; speedup vs baseline: 2.0090x; 1.0169x over previous
//
#include <hip/hip_runtime.h>
#include <stdint.h>

// Problem constants (fixed by the reference).
#define BB 4
#define NN 4096
#define MM 4096
#define CC 16
#define KMAX 128

// Output layout (flat float32, reference return order).
static constexpr int LOCSR_OFF = 0;                        // B*N*3
static constexpr int DATAR_OFF = BB * NN * 3;              // 49152
static constexpr int IDXS_OFF  = DATAR_OFF + BB * NN * CC; // 311296
static constexpr int NB_OFF    = IDXS_OFF + BB * NN;       // 327680

// radius as f32 (jnp weak-scalar cast), R^2 as double product cast to f32
static constexpr float RAD_F = 0.14f;
static constexpr float R2F   = (float)(0.14 * 0.14);

// ---------------- K1: bbox + params + keys + stable rank sort + scatter ----------------
// k_bbox dispatch eliminated: each block already loads its batch's full locs
// (3 x float4 per thread) for key computation, so the batch bbox is reduced
// from those same registers (per-thread min/max over 12 values -> wave
// shfl_xor reduce -> 16 LDS partials -> t0). min/max are exact under any
// reduction order, so grid params are bit-identical to the verified version.
__global__ void __launch_bounds__(1024) k_rank(const float* __restrict__ locs,
                                               const float* __restrict__ data,
                                               float* __restrict__ out,
                                               float4* __restrict__ sp4,
                                               unsigned* __restrict__ cs_sorted,
                                               float* __restrict__ gp) {
    __shared__ uint4 keys4[NN / 4];  // 16 KB
    __shared__ int partial[16][64];  // 4 KB
    __shared__ int s_dst[64];
    __shared__ float wred[16][6];    // per-wave bbox partials
    __shared__ float sp_low[3], sp_gdf[3];
    __shared__ int sp_s0, sp_s1;
    int blk = blockIdx.x;
    int b = blk >> 6;
    int t = threadIdx.x;
    int wave = t >> 6, lane = t & 63;

    // Single coalesced pass over this batch's locs (particles 4t..4t+3).
    const float4* lp = (const float4*)(locs + b * NN * 3) + t * 3;
    float4 A = lp[0], Bv = lp[1], Cv = lp[2];
    float ex[4] = {A.x, A.w, Bv.z, Cv.y};
    float ey[4] = {A.y, Bv.x, Bv.w, Cv.z};
    float ez[4] = {A.z, Bv.y, Cv.x, Cv.w};

    // ---- bbox: per-thread -> wave -> block ----
    float mn0 = fminf(fminf(ex[0], ex[1]), fminf(ex[2], ex[3]));
    float mx0 = fmaxf(fmaxf(ex[0], ex[1]), fmaxf(ex[2], ex[3]));
    float mn1 = fminf(fminf(ey[0], ey[1]), fminf(ey[2], ey[3]));
    float mx1 = fmaxf(fmaxf(ey[0], ey[1]), fmaxf(ey[2], ey[3]));
    float mn2 = fminf(fminf(ez[0], ez[1]), fminf(ez[2], ez[3]));
    float mx2 = fmaxf(fmaxf(ez[0], ez[1]), fmaxf(ez[2], ez[3]));
#pragma unroll
    for (int off = 32; off > 0; off >>= 1) {
        mn0 = fminf(mn0, __shfl_xor(mn0, off));
        mx0 = fmaxf(mx0, __shfl_xor(mx0, off));
        mn1 = fminf(mn1, __shfl_xor(mn1, off));
        mx1 = fmaxf(mx1, __shfl_xor(mx1, off));
        mn2 = fminf(mn2, __shfl_xor(mn2, off));
        mx2 = fmaxf(mx2, __shfl_xor(mx2, off));
    }
    if (lane == 0) {
        wred[wave][0] = mn0; wred[wave][1] = mn1; wred[wave][2] = mn2;
        wred[wave][3] = mx0; wred[wave][4] = mx1; wred[wave][5] = mx2;
    }
    __syncthreads();

    if (t == 0) {
        float a0 = 1e30f, a1 = 1e30f, a2 = 1e30f;
        float u0 = -1e30f, u1 = -1e30f, u2 = -1e30f;
#pragma unroll
        for (int k = 0; k < 16; ++k) {
            a0 = fminf(a0, wred[k][0]);
            a1 = fminf(a1, wred[k][1]);
            a2 = fminf(a2, wred[k][2]);
            u0 = fmaxf(u0, wred[k][3]);
            u1 = fmaxf(u1, wred[k][4]);
            u2 = fmaxf(u2, wred[k][5]);
        }
        float lo[3] = {a0, a1, a2}, up[3] = {u0, u1, u2};
        float low2[3], gdf[3];
        int gdi[3];
#pragma unroll
        for (int d = 0; d < 3; ++d) {
            // EXACT op sequence from the verified kernel
            float u = __fdiv_rn(__fsub_rn(up[d], lo[d]), RAD_F);
            u = fminf(fmaxf(u, 0.0f), 96.0f);
            float g = ceilf(u);
            float center = __fmul_rn(__fadd_rn(lo[d], up[d]), 0.5f);
            low2[d] = __fsub_rn(center, __fmul_rn(__fmul_rn(g, RAD_F), 0.5f));
            gdf[d] = g;
            gdi[d] = max((int)g, 1);
        }
        sp_low[0] = low2[0]; sp_low[1] = low2[1]; sp_low[2] = low2[2];
        sp_gdf[0] = gdf[0];  sp_gdf[1] = gdf[1];  sp_gdf[2] = gdf[2];
        sp_s0 = gdi[1] * gdi[2];
        sp_s1 = gdi[2];
        if ((blk & 63) == 0) {
            float* o = gp + b * 12;
            o[0] = low2[0]; o[1] = low2[1]; o[2] = low2[2];
            o[3] = gdf[0];  o[4] = gdf[1];  o[5] = gdf[2];
            ((int*)o)[6]  = gdi[1] * gdi[2];
            ((int*)o)[7]  = gdi[2];
            ((int*)o)[8]  = gdi[0] * gdi[1] * gdi[2];
            ((int*)o)[9]  = gdi[0];
            ((int*)o)[10] = gdi[1];
            ((int*)o)[11] = gdi[2];
        }
    }
    __syncthreads();

    // ---- keys from the registers already held ----
    {
        float l0 = sp_low[0], l1 = sp_low[1], l2 = sp_low[2];
        float g0 = sp_gdf[0], g1 = sp_gdf[1], g2 = sp_gdf[2];
        int s0 = sp_s0, s1 = sp_s1;
        unsigned kk[4];
#pragma unroll
        for (int j = 0; j < 4; ++j) {
            float c0 = fminf(fmaxf(floorf(__fdiv_rn(__fsub_rn(ex[j], l0), RAD_F)), 0.0f), __fsub_rn(g0, 1.0f));
            float c1 = fminf(fmaxf(floorf(__fdiv_rn(__fsub_rn(ey[j], l1), RAD_F)), 0.0f), __fsub_rn(g1, 1.0f));
            float c2 = fminf(fmaxf(floorf(__fdiv_rn(__fsub_rn(ez[j], l2), RAD_F)), 0.0f), __fsub_rn(g2, 1.0f));
            unsigned cell = (unsigned)((int)c0 * s0 + (int)c1 * s1 + (int)c2);
            kk[j] = cell * 4096u + (unsigned)(4 * t + j);
        }
        keys4[t] = make_uint4(kk[0], kk[1], kk[2], kk[3]);
    }
    __syncthreads();

    int i = (blk & 63) * 64 + lane;
    unsigned key = ((const unsigned*)keys4)[i];
    // Wave's 256-key chunk held in registers: one b128 per lane.
    uint4 mv = keys4[wave * 64 + lane];
    int rank = 0;
#pragma unroll
    for (int s = 0; s < 64; ++s) {
        unsigned a  = (unsigned)__builtin_amdgcn_readlane((int)mv.x, s);
        unsigned b2 = (unsigned)__builtin_amdgcn_readlane((int)mv.y, s);
        unsigned c2 = (unsigned)__builtin_amdgcn_readlane((int)mv.z, s);
        unsigned d2 = (unsigned)__builtin_amdgcn_readlane((int)mv.w, s);
        rank += (int)(a < key) + (int)(b2 < key) + (int)(c2 < key) + (int)(d2 < key);
    }
    partial[wave][lane] = rank;
    __syncthreads();
    if (wave == 0) {
        int r = 0;
#pragma unroll
        for (int w = 0; w < 16; ++w) r += partial[w][lane];
        s_dst[lane] = r;
    }
    __syncthreads();
    if (wave == 0) {
        int src = b * NN + i;
        int dst = b * NN + s_dst[lane];
        float x = locs[src * 3 + 0], y = locs[src * 3 + 1], z = locs[src * 3 + 2];
        out[IDXS_OFF + dst] = (float)i;        // idxs[new] = old (as f32)
        out[LOCSR_OFF + dst * 3 + 0] = x;
        out[LOCSR_OFF + dst * 3 + 1] = y;
        out[LOCSR_OFF + dst * 3 + 2] = z;
        cs_sorted[dst] = key;                  // combined key; cell = key>>12
        // pn = (x*x + y*y) + z*z, numpy pairwise-sum (forward) order
        float pn = __fadd_rn(__fadd_rn(__fmul_rn(x, x), __fmul_rn(y, y)), __fmul_rn(z, z));
        sp4[dst] = make_float4(x, y, z, pn);
    } else if (wave <= 4) {
        int p = lane;
        int ii = (blk & 63) * 64 + p;
        int dst = b * NN + s_dst[p];
        int c = wave - 1;
        const float4* dsrc = (const float4*)(data + (b * NN + ii) * 16);
        float4* ddst = (float4*)(out + DATAR_OFF + dst * 16);
        ddst[c] = dsrc[c];
    }
}

// ---------------- K2: grid-pruned radius search, wave per query ----------------
// 512-thread blocks, 8 queries/block: the 16 KB key-stage is amortized over
// 8 waves (staging L2 traffic halved vs 4-query blocks). (512,6) keeps the
// same 24 waves/CU and <=85 VGPR budget as the verified (256,6) config.
// Column bounds via 12-step in-LDS binary search (bit-exact lower_bound);
// packed candidate list and dist2 math unchanged from the verified version.
__device__ inline void axis_range(float qd, float lo, int gd, int* c0, int* c1) {
    const float DL = RAD_F + 1e-4f; // conservative margin >> all fp rounding
    float vlo = (qd - DL - lo) / RAD_F;
    float vhi = (qd + DL - lo) / RAD_F;
    int a = (int)floorf(vlo), b = (int)floorf(vhi);
    *c0 = min(max(a, 0), gd - 1);
    *c1 = min(max(b, 0), gd - 1);
}

__global__ void __launch_bounds__(512, 6) k_neighbors(const float* __restrict__ qlocs,
                                                      const float4* __restrict__ sp4,
                                                      const unsigned* __restrict__ cs_sorted,
                                                      const float* __restrict__ gp,
                                                      float* __restrict__ out) {
    __shared__ uint4 skeys4[NN / 4];  // 16 KB: batch's sorted combined keys
    const unsigned* skeys = (const unsigned*)skeys4;

    int blk = blockIdx.x;        // 2048 total: b = blk>>9, 8 queries/block
    int b = blk >> 9;
    int t = threadIdx.x;
    int wave = t >> 6, lane = t & 63;

    // Stage cs_sorted[b] into LDS (coalesced uint4, 8 per thread).
    {
        const uint4* g = (const uint4*)(cs_sorted + b * NN);
#pragma unroll
        for (int j = 0; j < 8; ++j) skeys4[t + 512 * j] = g[t + 512 * j];
    }

    int m = (blk & 511) * 8 + wave;
    const float* o = gp + b * 12;
    const int* oi = (const int*)o;
    int s0 = oi[6], s1 = oi[7];
    int gd0 = oi[9], gd1 = oi[10], gd2 = oi[11];
    const float* q = qlocs + (b * MM + m) * 3;
    float q0 = q[0], q1 = q[1], q2 = q[2];
    float qn = __fadd_rn(__fadd_rn(__fmul_rn(q0, q0), __fmul_rn(q1, q1)), __fmul_rn(q2, q2));
    int cx0, cx1, cy0, cy1, cz0, cz1;
    axis_range(q0, o[0], gd0, &cx0, &cx1);
    axis_range(q1, o[1], gd1, &cy0, &cy1);
    axis_range(q2, o[2], gd2, &cz0, &cz1);
    const float4* sp = sp4 + b * NN;
    float* nb = out + NB_OFF + (b * MM + m) * KMAX;

    // Per-column cell-index bounds (all lanes compute all 9, const-indexed).
    unsigned t0_[9], t1_[9];
    bool va_[9];
#pragma unroll
    for (int dx = 0; dx < 3; ++dx) {
#pragma unroll
        for (int dy = 0; dy < 3; ++dy) {
            int k = dx * 3 + dy;
            int cx = cx0 + dx, cy = cy0 + dy;
            bool v = (cx <= cx1) && (cy <= cy1);
            int base = cx * s0 + cy * s1;
            va_[k] = v;
            t0_[k] = v ? (unsigned)(base + cz0) * 4096u : 0u;       // lower_bound target
            t1_[k] = v ? (unsigned)(base + cz1 + 1) * 4096u : 0u;
        }
    }
    __syncthreads();   // LDS staging complete

    // Lane k (k<9) searches start bound of column k; lane 16+k its end bound.
    unsigned tgt = 0u;
#pragma unroll
    for (int k = 0; k < 9; ++k) {
        tgt = (lane == k)      ? t0_[k] : tgt;
        tgt = (lane == 16 + k) ? t1_[k] : tgt;
    }
    int lo = 0, hi = NN;      // lower_bound: first idx with skeys[idx] >= tgt
#pragma unroll
    for (int it = 0; it < 12; ++it) {  // 4096 -> exactly 12 halvings
        int mid = (lo + hi) >> 1;
        unsigned v = skeys[mid];
        bool c = v < tgt;
        lo = c ? mid + 1 : lo;
        hi = c ? hi : mid;
    }
    int res = lo;

    // Broadcast bounds to all lanes; invalid columns -> empty.
    int ps_[9], pe_[9];
#pragma unroll
    for (int k = 0; k < 9; ++k) {
        int a = __shfl(res, k);
        int e = __shfl(res, 16 + k);
        ps_[k] = va_[k] ? a : 0;
        pe_[k] = va_[k] ? e : 0;
    }
    int pre_[10];
    pre_[0] = 0;
#pragma unroll
    for (int k = 0; k < 9; ++k) pre_[k + 1] = pre_[k] + max(pe_[k] - ps_[k], 0);
    int T = pre_[9];

    int count = 0;
    for (int l0i = 0; l0i < T; l0i += 64) {
        int l = l0i + lane;
        // Map packed index l -> sorted particle index p (unrolled select chain).
        int p = 0;
#pragma unroll
        for (int k = 0; k < 9; ++k) {
            bool in = (l >= pre_[k]) && (l < pre_[k + 1]);
            p = in ? (ps_[k] + (l - pre_[k])) : p;
        }
        float4 P = sp[p];
        float cross = fmaf(q2, P.z, fmaf(q1, P.y, __fmul_rn(q0, P.x)));
        float dist2 = __fsub_rn(__fadd_rn(qn, P.w), __fmul_rn(2.0f, cross));
        bool hit = (l < T) && (dist2 <= R2F);
        unsigned long long bal = __ballot(hit);
        if (hit) {
            int pos = count + __popcll(bal & ((1ull << lane) - 1ull));
            if (pos < KMAX) nb[pos] = (float)p;
        }
        count += __popcll(bal);
        if (count >= KMAX) break; // wave-uniform; remaining hits can't land
    }
    for (int j = count + lane; j < KMAX; j += 64) nb[j] = -1.0f;
}

extern "C" void kernel_launch(void* const* d_in, const int* in_sizes, int n_in,
                              void* d_out, int out_size, void* d_ws, size_t ws_size,
                              hipStream_t stream) {
    const float* locs  = (const float*)d_in[0];
    const float* data  = (const float*)d_in[1];
    const float* qlocs = (const float*)d_in[2];
    float* out = (float*)d_out;
    char* ws = (char*)d_ws;
    // ws layout
    float*    gp        = (float*)ws;                          // 4*12 floats (512 B reserved)
    unsigned* cs_sorted = (unsigned*)(ws + 512);               // 64 KB
    float4*   sp4       = (float4*)(ws + 512 + 65536);         // 256 KB (16B aligned)

    k_rank<<<BB * 64, 1024, 0, stream>>>(locs, data, out, sp4, cs_sorted, gp);
    k_neighbors<<<BB * 512, 512, 0, stream>>>(qlocs, sp4, cs_sorted, gp, out);
}